// Round 10
// baseline (197.083 us; speedup 1.0000x reference)
//
#include <hip/hip_runtime.h>

#define Nn 2048
#define FIN 512
#define FO 64
#define SHIFT 20.0f
#define NJT 32
#define PBS2 72               // bf16 row stride in shorts: 144B rows
#define ZTOT (Nn * FO + Nn)   // osum + lsum floats (fallback path only)

// bf16-tile XOR swizzles (short index), applied identically on write and read.
// hj16: e-phase reads rows 4*lj+d at fixed f-block -> XOR 8-short block with (r>>2)&7.
#define HJX(r, f) ((r) * PBS2 + ((((f) >> 3) ^ (((r) >> 2) & 7)) << 3) + ((f) & 7))
// pT16 [j][i]: PV reads are j-uniform (broadcast-free); XOR spreads the transpose writes.
#define PX16(j, i) ((j) * PBS2 + ((((i) >> 3) ^ ((j) & 7)) << 3) + ((i) & 7))

__device__ __forceinline__ unsigned pk2(float x, float y) {   // 2 f32 -> packed bf16 (RNE)
    unsigned r;
    asm("v_cvt_pk_bf16_f32 %0, %1, %2" : "=v"(r) : "v"(x), "v"(y));
    return r;
}
__device__ __forceinline__ float bflo(unsigned u) { return __uint_as_float(u << 16); }
__device__ __forceinline__ float bfhi(unsigned u) { return __uint_as_float(u & 0xffff0000u); }

// ---------------- K1: h = x @ W  (proven) + optional zeroing (fallback path) ----------------
__global__ __launch_bounds__(256) void gat_xw(const float* __restrict__ x,
                                              const float* __restrict__ W,
                                              float* __restrict__ h,
                                              float* __restrict__ z) {
    const int gt = blockIdx.x * 256 + threadIdx.x;
    if (z != nullptr && gt < ZTOT) z[gt] = 0.f;

    __shared__ float part[2][2][FO];
    const int wave = threadIdx.x >> 6;
    const int lane = threadIdx.x & 63;
    const int rs = wave >> 1;
    const int kh = wave & 1;
    int row = blockIdx.x * 2 + rs;
    row = __builtin_amdgcn_readfirstlane(row);
    const float* xr = x + (size_t)row * FIN + kh * (FIN / 2);
    const float* Wp = W + (size_t)kh * (FIN / 2) * FO;
    float acc = 0.f;
#pragma unroll 2
    for (int k = 0; k < FIN / 2; k += 8) {
        float4 xa = *(const float4*)(xr + k);
        float4 xb = *(const float4*)(xr + k + 4);
        acc = fmaf(xa.x, Wp[(k + 0) * FO + lane], acc);
        acc = fmaf(xa.y, Wp[(k + 1) * FO + lane], acc);
        acc = fmaf(xa.z, Wp[(k + 2) * FO + lane], acc);
        acc = fmaf(xa.w, Wp[(k + 3) * FO + lane], acc);
        acc = fmaf(xb.x, Wp[(k + 4) * FO + lane], acc);
        acc = fmaf(xb.y, Wp[(k + 5) * FO + lane], acc);
        acc = fmaf(xb.z, Wp[(k + 6) * FO + lane], acc);
        acc = fmaf(xb.w, Wp[(k + 7) * FO + lane], acc);
    }
    part[rs][kh][lane] = acc;
    __syncthreads();
    if (threadIdx.x < 128) {
        const int r2 = threadIdx.x >> 6;
        const int l2 = threadIdx.x & 63;
        h[((size_t)blockIdx.x * 2 + r2) * FO + l2] = part[r2][0][l2] + part[r2][1][l2];
    }
}

// ---------------- K2: high-occupancy attn -- bf16 LDS tiles, hi from L1, 24 waves/CU ----------------
// Block = 256 thr = 4 waves, tile 64i x 64j (NJT=32 -> 1024 blocks). LDS shrunk to
// ~18.9KB (hj + pT in bf16, hi read from global: i-tile is 16KB, L1-resident after the
// first f-pass; 16-lane-broadcast addresses). launch_bounds(256,6) -> 6 blocks/CU =
// 24 waves/CU (1.5x the 16-wave plateau of rounds 2..9). DS ops are b64 (~6cyc) and
// halved in count. bf16 error budget: e-err ~0.008 -> out err ~0.03 << 0.13 threshold.
// Lane maps identical to round-4 (proven): e-phase (li,lj) owns 4i x 4j; PV owns 4i x 4f.
// pT write->read is same-wave cells (no barrier, proven r6/r7/r9); ONE barrier total.
template <bool ATOMIC>
__global__ __launch_bounds__(256, 6) void gat_attn10(const float* __restrict__ h,
                                                     const int* __restrict__ adj,
                                                     const float* __restrict__ a,
                                                     float* __restrict__ po,
                                                     float* __restrict__ pl) {
    __shared__ __align__(16) short hj16[64 * PBS2];   // bf16 hj tile, HJX swizzle
    __shared__ __align__(16) short pT16[64 * PBS2];   // bf16 p^T tile [j][i], PX16 swizzle
    __shared__ float a_s[FO];

    const int tid = threadIdx.x;
    const int w = tid >> 6;
    const int lane = tid & 63;
    const int li = lane & 3;
    const int lj = lane >> 2;
    const int it = blockIdx.x >> 5;          // 0..31
    const int jt = blockIdx.x & (NJT - 1);   // 0..31
    const int ib = it * 64;
    const int jb = jt * 64;
    const int iw = w * 16;

    // stage hj tile as bf16 (4 float4 loads / thread, cvt_pk, b64 swizzled writes)
    for (int g4 = tid; g4 < 1024; g4 += 256) {
        const int row = g4 >> 4;
        const int f0 = (g4 & 15) * 4;
        const float4 u = *(const float4*)(h + (size_t)jb * FO + (size_t)g4 * 4);
        uint2 pk;
        pk.x = pk2(u.x, u.y);
        pk.y = pk2(u.z, u.w);
        *(uint2*)&hj16[HJX(row, f0)] = pk;
    }
    if (tid < FO) a_s[tid] = a[tid];
    __syncthreads();   // the only block-wide barrier

    // ---- e-phase: e[di][dj] = sum_f a_f * |hi - hj| ; hi from global (L1), hj bf16 LDS ----
    float e[4][4];
#pragma unroll
    for (int di = 0; di < 4; di++)
#pragma unroll
        for (int dj = 0; dj < 4; dj++) e[di][dj] = 0.f;

    const float* hib = h + (size_t)(ib + iw + 4 * li) * FO;   // this lane's 4 i-rows

#pragma unroll 4
    for (int f4 = 0; f4 < 16; f4++) {
        const float4 av = *(const float4*)&a_s[f4 * 4];
        float4 hi4[4], hj4[4];
#pragma unroll
        for (int d = 0; d < 4; d++) {
            hi4[d] = *(const float4*)(hib + (size_t)d * FO + f4 * 4);   // 16-lane broadcast, L1-hot
            const uint2 hw = *(const uint2*)&hj16[HJX(4 * lj + d, f4 * 4)];
            hj4[d].x = bflo(hw.x); hj4[d].y = bfhi(hw.x);
            hj4[d].z = bflo(hw.y); hj4[d].w = bfhi(hw.y);
        }
#pragma unroll
        for (int di = 0; di < 4; di++)
#pragma unroll
            for (int dj = 0; dj < 4; dj++) {
                e[di][dj] = fmaf(fabsf(hi4[di].x - hj4[dj].x), av.x, e[di][dj]);
                e[di][dj] = fmaf(fabsf(hi4[di].y - hj4[dj].y), av.y, e[di][dj]);
                e[di][dj] = fmaf(fabsf(hi4[di].z - hj4[dj].z), av.z, e[di][dj]);
                e[di][dj] = fmaf(fabsf(hi4[di].w - hj4[dj].w), av.w, e[di][dj]);
            }
    }

    // ---- p = adj ? exp(relu(e) - SHIFT) : 0 ; fp32 ls; bf16 pT transpose-write ----
    float ls[4];
#pragma unroll
    for (int di = 0; di < 4; di++) ls[di] = 0.f;
#pragma unroll
    for (int di = 0; di < 4; di++) {
        const int4 am = *(const int4*)(adj + (size_t)(ib + iw + 4 * li + di) * Nn + (jb + 4 * lj));
        const int* ap = (const int*)&am;
#pragma unroll
        for (int dj = 0; dj < 4; dj++) {
            const float p = (ap[dj] > 0) ? __expf(fmaxf(e[di][dj], 0.f) - SHIFT) : 0.f;
            e[di][dj] = p;
            ls[di] += p;
        }
    }
#pragma unroll
    for (int dj = 0; dj < 4; dj++) {
        uint2 pk;
        pk.x = pk2(e[0][dj], e[1][dj]);
        pk.y = pk2(e[2][dj], e[3][dj]);
        *(uint2*)&pT16[PX16(4 * lj + dj, iw + 4 * li)] = pk;   // same-wave cells, DS FIFO
    }

    // ---- PV: lane -> (4i x 4f): i = iw+4*li+di, f = 4*lj+c ; p and hj from bf16 LDS ----
    float pv[4][4];
#pragma unroll
    for (int u = 0; u < 4; u++)
#pragma unroll
        for (int v2 = 0; v2 < 4; v2++) pv[u][v2] = 0.f;

#pragma unroll 4
    for (int j = 0; j < 64; j++) {
        const uint2 pw = *(const uint2*)&pT16[PX16(j, iw + 4 * li)];
        const uint2 hw = *(const uint2*)&hj16[HJX(j, 4 * lj)];
        const float p0 = bflo(pw.x), p1 = bfhi(pw.x), p2 = bflo(pw.y), p3 = bfhi(pw.y);
        const float h0 = bflo(hw.x), h1 = bfhi(hw.x), h2 = bflo(hw.y), h3 = bfhi(hw.y);
        pv[0][0] = fmaf(p0, h0, pv[0][0]); pv[0][1] = fmaf(p0, h1, pv[0][1]);
        pv[0][2] = fmaf(p0, h2, pv[0][2]); pv[0][3] = fmaf(p0, h3, pv[0][3]);
        pv[1][0] = fmaf(p1, h0, pv[1][0]); pv[1][1] = fmaf(p1, h1, pv[1][1]);
        pv[1][2] = fmaf(p1, h2, pv[1][2]); pv[1][3] = fmaf(p1, h3, pv[1][3]);
        pv[2][0] = fmaf(p2, h0, pv[2][0]); pv[2][1] = fmaf(p2, h1, pv[2][1]);
        pv[2][2] = fmaf(p2, h2, pv[2][2]); pv[2][3] = fmaf(p2, h3, pv[2][3]);
        pv[3][0] = fmaf(p3, h0, pv[3][0]); pv[3][1] = fmaf(p3, h1, pv[3][1]);
        pv[3][2] = fmaf(p3, h2, pv[3][2]); pv[3][3] = fmaf(p3, h3, pv[3][3]);
    }

    // ---- epilogue: reduce ls over lj lanes (round-4-proven); partial stores ----
#pragma unroll
    for (int di = 0; di < 4; di++) {
        float v = ls[di];
        v += __shfl_xor(v, 4, 64);
        v += __shfl_xor(v, 8, 64);
        v += __shfl_xor(v, 16, 64);
        v += __shfl_xor(v, 32, 64);
        ls[di] = v;
    }

    if constexpr (!ATOMIC) {
        if (lj == 0) {
#pragma unroll
            for (int di = 0; di < 4; di++)
                pl[(size_t)jt * Nn + (ib + iw + 4 * li + di)] = ls[di];
        }
#pragma unroll
        for (int di = 0; di < 4; di++)
            *(float4*)&po[((size_t)jt * Nn + (ib + iw + 4 * li + di)) * FO + 4 * lj] =
                make_float4(pv[di][0], pv[di][1], pv[di][2], pv[di][3]);
    } else {
        if (lj == 0) {
#pragma unroll
            for (int di = 0; di < 4; di++)
                atomicAdd(&pl[ib + iw + 4 * li + di], ls[di]);
        }
#pragma unroll
        for (int di = 0; di < 4; di++) {
#pragma unroll
            for (int v2 = 0; v2 < 4; v2++)
                atomicAdd(&po[(size_t)(ib + iw + 4 * li + di) * FO + 4 * lj + v2], pv[di][v2]);
        }
    }
}

// ---------------- K3: out = relu(sum_jt po / sum_jt pl) ----------------
__global__ __launch_bounds__(256) void gat_reduce(const float* __restrict__ po,
                                                  const float* __restrict__ pl,
                                                  float* __restrict__ out) {
    const int t = blockIdx.x * 256 + threadIdx.x;   // grid 512 -> 131072 = Nn*FO
    const int i = t >> 6;
    float s = 0.f;
#pragma unroll
    for (int p = 0; p < NJT; p++) s += po[(size_t)p * (Nn * FO) + t];
    float l = 0.f;
#pragma unroll
    for (int p = 0; p < NJT; p++) l += pl[p * Nn + i];   // wave-uniform addr -> broadcast
    out[t] = fmaxf(s / l, 0.f);
}

// ---------------- fallback K3: out = relu(osum / lsum) ----------------
__global__ __launch_bounds__(256) void gat_fin(const float* __restrict__ osum,
                                               const float* __restrict__ lsum,
                                               float* __restrict__ out) {
    const int t = blockIdx.x * 256 + threadIdx.x;
    out[t] = fmaxf(osum[t] / lsum[t >> 6], 0.f);
}

extern "C" void kernel_launch(void* const* d_in, const int* in_sizes, int n_in,
                              void* d_out, int out_size, void* d_ws, size_t ws_size,
                              hipStream_t stream) {
    const float* x   = (const float*)d_in[0];
    const int*   adj = (const int*)d_in[1];
    const float* W   = (const float*)d_in[2];
    const float* a   = (const float*)d_in[3];
    float* out = (float*)d_out;

    float* h = (float*)d_ws;                                   // Nn*FO floats
    const size_t need = ((size_t)Nn * FO + (size_t)NJT * Nn * FO + (size_t)NJT * Nn) * 4;

    if (ws_size >= need) {
        // no-atomic path: private partials + reduction
        float* po = h + (size_t)Nn * FO;                       // NJT*Nn*FO floats
        float* pl = po + (size_t)NJT * Nn * FO;                // NJT*Nn floats
        gat_xw<<<dim3(1024), dim3(256), 0, stream>>>(x, W, h, nullptr);
        gat_attn10<false><<<dim3(32 * NJT), dim3(256), 0, stream>>>(h, adj, a, po, pl);
        gat_reduce<<<dim3(512), dim3(256), 0, stream>>>(po, pl, out);
    } else {
        // fallback: atomic accumulation (1.06 MB workspace)
        float* osum = h + (size_t)Nn * FO;
        float* lsum = osum + (size_t)Nn * FO;
        gat_xw<<<dim3(1024), dim3(256), 0, stream>>>(x, W, h, osum);   // zeros osum+lsum
        gat_attn10<true><<<dim3(32 * NJT), dim3(256), 0, stream>>>(h, adj, a, osum, lsum);
        gat_fin<<<dim3(512), dim3(256), 0, stream>>>(osum, lsum, out);
    }
}

// Round 11
// 121.647 us; speedup vs baseline: 1.6201x; 1.6201x over previous
//
#include <hip/hip_runtime.h>

#define Nn 2048
#define FIN 512
#define FO 64
#define SHIFT 20.0f
#define NJT 32
#define HS 68                 // hi_s fp32 row stride: 272B, 16B-aligned float4 blocks
#define PBS2 72               // bf16 row stride in shorts: 144B rows
#define ZTOT (Nn * FO + Nn)   // osum + lsum floats (fallback path only)

// round-4-proven fp32 f4-block XOR swizzle (read/write consistent)
#define HX(r, f) ((r) * HS + ((((f) >> 2) ^ (((r) >> 2) & 15)) << 2))
// round-10-proven bf16 swizzles (short index), write/read consistent
#define HJX(r, f)  ((r) * PBS2 + ((((f) >> 3) ^ (((r) >> 2) & 7)) << 3) + ((f) & 7))
#define PX16(j, i) ((j) * PBS2 + ((((i) >> 3) ^ ((j) & 7)) << 3) + ((i) & 7))

__device__ __forceinline__ unsigned pk2(float x, float y) {   // 2 f32 -> packed bf16 (RNE)
    unsigned r;
    asm("v_cvt_pk_bf16_f32 %0, %1, %2" : "=v"(r) : "v"(x), "v"(y));
    return r;
}
__device__ __forceinline__ float bflo(unsigned u) { return __uint_as_float(u << 16); }
__device__ __forceinline__ float bfhi(unsigned u) { return __uint_as_float(u & 0xffff0000u); }

// ---------------- K1: h = x @ W  (proven) + optional zeroing (fallback path) ----------------
__global__ __launch_bounds__(256) void gat_xw(const float* __restrict__ x,
                                              const float* __restrict__ W,
                                              float* __restrict__ h,
                                              float* __restrict__ z) {
    const int gt = blockIdx.x * 256 + threadIdx.x;
    if (z != nullptr && gt < ZTOT) z[gt] = 0.f;

    __shared__ float part[2][2][FO];
    const int wave = threadIdx.x >> 6;
    const int lane = threadIdx.x & 63;
    const int rs = wave >> 1;
    const int kh = wave & 1;
    int row = blockIdx.x * 2 + rs;
    row = __builtin_amdgcn_readfirstlane(row);
    const float* xr = x + (size_t)row * FIN + kh * (FIN / 2);
    const float* Wp = W + (size_t)kh * (FIN / 2) * FO;
    float acc = 0.f;
#pragma unroll 2
    for (int k = 0; k < FIN / 2; k += 8) {
        float4 xa = *(const float4*)(xr + k);
        float4 xb = *(const float4*)(xr + k + 4);
        acc = fmaf(xa.x, Wp[(k + 0) * FO + lane], acc);
        acc = fmaf(xa.y, Wp[(k + 1) * FO + lane], acc);
        acc = fmaf(xa.z, Wp[(k + 2) * FO + lane], acc);
        acc = fmaf(xa.w, Wp[(k + 3) * FO + lane], acc);
        acc = fmaf(xb.x, Wp[(k + 4) * FO + lane], acc);
        acc = fmaf(xb.y, Wp[(k + 5) * FO + lane], acc);
        acc = fmaf(xb.z, Wp[(k + 6) * FO + lane], acc);
        acc = fmaf(xb.w, Wp[(k + 7) * FO + lane], acc);
    }
    part[rs][kh][lane] = acc;
    __syncthreads();
    if (threadIdx.x < 128) {
        const int r2 = threadIdx.x >> 6;
        const int l2 = threadIdx.x & 63;
        h[((size_t)blockIdx.x * 2 + r2) * FO + l2] = part[r2][0][l2] + part[r2][1][l2];
    }
}

// ---------------- K2: round-4 structure, bf16 hj/pT in LDS, pT unioned over hi ----------------
// Block = 256 thr = 4 waves, tile 64i x 64j (NJT=32 -> 1024 blocks). ALL hot operands in
// LDS (round-10's global-hi thrashed L1/L2 -> HBM-bound; reverted). DS BYTES halved on the
// hj/pT streams (the pipe is byte-bandwidth-bound: r4 b64->b128 at equal bytes was neutral):
//   hi fp32 [64x68] HX (17.4KB, proven) ; hj bf16 [64x72] HJX (9.2KB) ;
//   pT bf16 UNIONED over hi_s (dead after e-phase, r2-proven barrier).
// LDS 26.9KB -> 5 blocks/CU = 20 waves (was 16). DS cyc/lane ~3216 -> ~2016.
// Numerics: bf16 hj + bf16 p proven in r10 (absmax 0.047 < 0.13). Lane maps, mask, ls
// reduce, partial stores: round-4-proven verbatim.
template <bool ATOMIC>
__global__ __launch_bounds__(256, 5) void gat_attn11(const float* __restrict__ h,
                                                     const int* __restrict__ adj,
                                                     const float* __restrict__ a,
                                                     float* __restrict__ po,
                                                     float* __restrict__ pl) {
    __shared__ __align__(16) float hi_s[64 * HS];     // fp32 hi tile; pT16 aliases after B1
    __shared__ __align__(16) short hj16[64 * PBS2];   // bf16 hj tile, HJX swizzle
    __shared__ float a_s[FO];
    short* pT16 = (short*)hi_s;                       // bf16 p^T tile [j][i], PX16 swizzle

    const int tid = threadIdx.x;
    const int w = tid >> 6;
    const int lane = tid & 63;
    const int li = lane & 3;
    const int lj = lane >> 2;
    const int it = blockIdx.x >> 5;          // 0..31
    const int jt = blockIdx.x & (NJT - 1);   // 0..31
    const int ib = it * 64;
    const int jb = jt * 64;
    const int iw = w * 16;

    // stage hi (fp32, HX) and hj (bf16, HJX)
    for (int g4 = tid; g4 < 1024; g4 += 256) {
        const int row = g4 >> 4;
        const int f0 = (g4 & 15) * 4;
        *(float4*)&hi_s[HX(row, f0)] = *(const float4*)(h + (size_t)ib * FO + (size_t)g4 * 4);
        const float4 u = *(const float4*)(h + (size_t)jb * FO + (size_t)g4 * 4);
        uint2 pk;
        pk.x = pk2(u.x, u.y);
        pk.y = pk2(u.z, u.w);
        *(uint2*)&hj16[HJX(row, f0)] = pk;
    }
    if (tid < FO) a_s[tid] = a[tid];
    __syncthreads();   // B0

    // ---- e-phase: e[di][dj] = sum_f a_f * |hi - hj| ; hi fp32 b128, hj bf16 b64 ----
    float e[4][4];
#pragma unroll
    for (int di = 0; di < 4; di++)
#pragma unroll
        for (int dj = 0; dj < 4; dj++) e[di][dj] = 0.f;

#pragma unroll 4
    for (int f4 = 0; f4 < 16; f4++) {
        const float4 av = *(const float4*)&a_s[f4 * 4];
        float4 hi4[4], hj4[4];
#pragma unroll
        for (int d = 0; d < 4; d++) {
            hi4[d] = *(const float4*)&hi_s[HX(iw + 4 * li + d, f4 * 4)];
            const uint2 hw = *(const uint2*)&hj16[HJX(4 * lj + d, f4 * 4)];
            hj4[d].x = bflo(hw.x); hj4[d].y = bfhi(hw.x);
            hj4[d].z = bflo(hw.y); hj4[d].w = bfhi(hw.y);
        }
#pragma unroll
        for (int di = 0; di < 4; di++)
#pragma unroll
            for (int dj = 0; dj < 4; dj++) {
                e[di][dj] = fmaf(fabsf(hi4[di].x - hj4[dj].x), av.x, e[di][dj]);
                e[di][dj] = fmaf(fabsf(hi4[di].y - hj4[dj].y), av.y, e[di][dj]);
                e[di][dj] = fmaf(fabsf(hi4[di].z - hj4[dj].z), av.z, e[di][dj]);
                e[di][dj] = fmaf(fabsf(hi4[di].w - hj4[dj].w), av.w, e[di][dj]);
            }
    }

    // ---- p = adj ? exp(relu(e) - SHIFT) : 0 ; fp32 ls (round-4-proven) ----
    float ls[4];
#pragma unroll
    for (int di = 0; di < 4; di++) ls[di] = 0.f;
#pragma unroll
    for (int di = 0; di < 4; di++) {
        const int4 am = *(const int4*)(adj + (size_t)(ib + iw + 4 * li + di) * Nn + (jb + 4 * lj));
        const int* ap = (const int*)&am;
#pragma unroll
        for (int dj = 0; dj < 4; dj++) {
            const float p = (ap[dj] > 0) ? __expf(fmaxf(e[di][dj], 0.f) - SHIFT) : 0.f;
            e[di][dj] = p;
            ls[di] += p;
        }
    }

    __syncthreads();   // B1: all waves done reading hi_s -> pT16 may overwrite (union)

    // bf16 pT transpose-write (same-wave cells; PV read needs no further barrier)
#pragma unroll
    for (int dj = 0; dj < 4; dj++) {
        uint2 pk;
        pk.x = pk2(e[0][dj], e[1][dj]);
        pk.y = pk2(e[2][dj], e[3][dj]);
        *(uint2*)&pT16[PX16(4 * lj + dj, iw + 4 * li)] = pk;
    }

    // ---- PV: lane -> (4i x 4f): i = iw+4*li+di, f = 4*lj+c ; p and hj bf16 b64 ----
    float pv[4][4];
#pragma unroll
    for (int u = 0; u < 4; u++)
#pragma unroll
        for (int v2 = 0; v2 < 4; v2++) pv[u][v2] = 0.f;

#pragma unroll 4
    for (int j = 0; j < 64; j++) {
        const uint2 pw = *(const uint2*)&pT16[PX16(j, iw + 4 * li)];
        const uint2 hw = *(const uint2*)&hj16[HJX(j, 4 * lj)];
        const float p0 = bflo(pw.x), p1 = bfhi(pw.x), p2 = bflo(pw.y), p3 = bfhi(pw.y);
        const float h0 = bflo(hw.x), h1 = bfhi(hw.x), h2 = bflo(hw.y), h3 = bfhi(hw.y);
        pv[0][0] = fmaf(p0, h0, pv[0][0]); pv[0][1] = fmaf(p0, h1, pv[0][1]);
        pv[0][2] = fmaf(p0, h2, pv[0][2]); pv[0][3] = fmaf(p0, h3, pv[0][3]);
        pv[1][0] = fmaf(p1, h0, pv[1][0]); pv[1][1] = fmaf(p1, h1, pv[1][1]);
        pv[1][2] = fmaf(p1, h2, pv[1][2]); pv[1][3] = fmaf(p1, h3, pv[1][3]);
        pv[2][0] = fmaf(p2, h0, pv[2][0]); pv[2][1] = fmaf(p2, h1, pv[2][1]);
        pv[2][2] = fmaf(p2, h2, pv[2][2]); pv[2][3] = fmaf(p2, h3, pv[2][3]);
        pv[3][0] = fmaf(p3, h0, pv[3][0]); pv[3][1] = fmaf(p3, h1, pv[3][1]);
        pv[3][2] = fmaf(p3, h2, pv[3][2]); pv[3][3] = fmaf(p3, h3, pv[3][3]);
    }

    // ---- epilogue: reduce ls over lj lanes (round-4-proven); partial stores ----
#pragma unroll
    for (int di = 0; di < 4; di++) {
        float v = ls[di];
        v += __shfl_xor(v, 4, 64);
        v += __shfl_xor(v, 8, 64);
        v += __shfl_xor(v, 16, 64);
        v += __shfl_xor(v, 32, 64);
        ls[di] = v;
    }

    if constexpr (!ATOMIC) {
        if (lj == 0) {
#pragma unroll
            for (int di = 0; di < 4; di++)
                pl[(size_t)jt * Nn + (ib + iw + 4 * li + di)] = ls[di];
        }
#pragma unroll
        for (int di = 0; di < 4; di++)
            *(float4*)&po[((size_t)jt * Nn + (ib + iw + 4 * li + di)) * FO + 4 * lj] =
                make_float4(pv[di][0], pv[di][1], pv[di][2], pv[di][3]);
    } else {
        if (lj == 0) {
#pragma unroll
            for (int di = 0; di < 4; di++)
                atomicAdd(&pl[ib + iw + 4 * li + di], ls[di]);
        }
#pragma unroll
        for (int di = 0; di < 4; di++) {
#pragma unroll
            for (int v2 = 0; v2 < 4; v2++)
                atomicAdd(&po[(size_t)(ib + iw + 4 * li + di) * FO + 4 * lj + v2], pv[di][v2]);
        }
    }
}

// ---------------- K3: out = relu(sum_jt po / sum_jt pl) ----------------
__global__ __launch_bounds__(256) void gat_reduce(const float* __restrict__ po,
                                                  const float* __restrict__ pl,
                                                  float* __restrict__ out) {
    const int t = blockIdx.x * 256 + threadIdx.x;   // grid 512 -> 131072 = Nn*FO
    const int i = t >> 6;
    float s = 0.f;
#pragma unroll
    for (int p = 0; p < NJT; p++) s += po[(size_t)p * (Nn * FO) + t];
    float l = 0.f;
#pragma unroll
    for (int p = 0; p < NJT; p++) l += pl[p * Nn + i];   // wave-uniform addr -> broadcast
    out[t] = fmaxf(s / l, 0.f);
}

// ---------------- fallback K3: out = relu(osum / lsum) ----------------
__global__ __launch_bounds__(256) void gat_fin(const float* __restrict__ osum,
                                               const float* __restrict__ lsum,
                                               float* __restrict__ out) {
    const int t = blockIdx.x * 256 + threadIdx.x;
    out[t] = fmaxf(osum[t] / lsum[t >> 6], 0.f);
}

extern "C" void kernel_launch(void* const* d_in, const int* in_sizes, int n_in,
                              void* d_out, int out_size, void* d_ws, size_t ws_size,
                              hipStream_t stream) {
    const float* x   = (const float*)d_in[0];
    const int*   adj = (const int*)d_in[1];
    const float* W   = (const float*)d_in[2];
    const float* a   = (const float*)d_in[3];
    float* out = (float*)d_out;

    float* h = (float*)d_ws;                                   // Nn*FO floats
    const size_t need = ((size_t)Nn * FO + (size_t)NJT * Nn * FO + (size_t)NJT * Nn) * 4;

    if (ws_size >= need) {
        // no-atomic path: private partials + reduction
        float* po = h + (size_t)Nn * FO;                       // NJT*Nn*FO floats
        float* pl = po + (size_t)NJT * Nn * FO;                // NJT*Nn floats
        gat_xw<<<dim3(1024), dim3(256), 0, stream>>>(x, W, h, nullptr);
        gat_attn11<false><<<dim3(32 * NJT), dim3(256), 0, stream>>>(h, adj, a, po, pl);
        gat_reduce<<<dim3(512), dim3(256), 0, stream>>>(po, pl, out);
    } else {
        // fallback: atomic accumulation (1.06 MB workspace)
        float* osum = h + (size_t)Nn * FO;
        float* lsum = osum + (size_t)Nn * FO;
        gat_xw<<<dim3(1024), dim3(256), 0, stream>>>(x, W, h, osum);   // zeros osum+lsum
        gat_attn11<true><<<dim3(32 * NJT), dim3(256), 0, stream>>>(h, adj, a, osum, lsum);
        gat_fin<<<dim3(512), dim3(256), 0, stream>>>(osum, lsum, out);
    }
}